// Round 2
// baseline (176.215 us; speedup 1.0000x reference)
//
#include <hip/hip_runtime.h>
#include <hip/hip_bf16.h>

#define B_DIM  8192
#define IN_DIM 1024
#define H_DIM  1024
#define K_DIM  2048   // IN + H
#define NT     (K_DIM / 64)

typedef __attribute__((ext_vector_type(8))) short bf16x8;
typedef __attribute__((ext_vector_type(4))) float f32x4;

__device__ __forceinline__ void mfma_16x16x32_bf16(f32x4& d, const bf16x8& a, const bf16x8& b) {
  asm("v_mfma_f32_16x16x32_bf16 %0, %1, %2, %0" : "+v"(d) : "v"(a), "v"(b));
}

__device__ __forceinline__ void gload16(const void* g, void* l) {
  __builtin_amdgcn_global_load_lds(
      (const __attribute__((address_space(1))) void*)g,
      (__attribute__((address_space(3))) void*)l,
      16, 0, 0);
}

__device__ __forceinline__ float fast_sigmoid(float x) {
  return 1.0f / (1.0f + __expf(-x));
}
__device__ __forceinline__ float fast_tanh(float x) {
  float e = __expf(2.0f * x);
  return 1.0f - 2.0f / (e + 1.0f);
}

// ---------------- pack kernels (unchanged from round 1) --------------------
__global__ __launch_bounds__(256) void pack_a_kernel(
    const float* __restrict__ x, const float* __restrict__ hx,
    __hip_bfloat16* __restrict__ A) {
  const int idx = blockIdx.x * 256 + threadIdx.x;
  const int r  = idx >> 8;
  const int kk = (idx & 255) << 3;
  const float* src = (kk < IN_DIM) ? (x + (size_t)r * IN_DIM + kk)
                                   : (hx + (size_t)r * H_DIM + (kk - IN_DIM));
  const float4 v0 = ((const float4*)src)[0];
  const float4 v1 = ((const float4*)src)[1];
  __hip_bfloat16 t[8];
  t[0] = __float2bfloat16(v0.x); t[1] = __float2bfloat16(v0.y);
  t[2] = __float2bfloat16(v0.z); t[3] = __float2bfloat16(v0.w);
  t[4] = __float2bfloat16(v1.x); t[5] = __float2bfloat16(v1.y);
  t[6] = __float2bfloat16(v1.z); t[7] = __float2bfloat16(v1.w);
  *(uint4*)(A + ((size_t)idx << 3)) = *(const uint4*)t;
}

__global__ __launch_bounds__(256) void pack_w_kernel(
    const float* __restrict__ wxi, const float* __restrict__ wxf,
    const float* __restrict__ wxc, const float* __restrict__ wxo,
    const float* __restrict__ whi, const float* __restrict__ whf,
    const float* __restrict__ whc, const float* __restrict__ who,
    __hip_bfloat16* __restrict__ W) {
  const int idx = blockIdx.x * 256 + threadIdx.x;
  const int row = idx >> 8;
  const int kk  = (idx & 255) << 3;
  const int g = row >> 10, n = row & 1023;
  const float* src;
  if (kk < IN_DIM) {
    const float* p = (g == 0) ? wxi : (g == 1) ? wxf : (g == 2) ? wxc : wxo;
    src = p + (size_t)n * IN_DIM + kk;
  } else {
    const float* p = (g == 0) ? whi : (g == 1) ? whf : (g == 2) ? whc : who;
    src = p + (size_t)n * H_DIM + (kk - IN_DIM);
  }
  const float4 v0 = ((const float4*)src)[0];
  const float4 v1 = ((const float4*)src)[1];
  __hip_bfloat16 t[8];
  t[0] = __float2bfloat16(v0.x); t[1] = __float2bfloat16(v0.y);
  t[2] = __float2bfloat16(v0.z); t[3] = __float2bfloat16(v0.w);
  t[4] = __float2bfloat16(v1.x); t[5] = __float2bfloat16(v1.y);
  t[6] = __float2bfloat16(v1.z); t[7] = __float2bfloat16(v1.w);
  *(uint4*)(W + ((size_t)idx << 3)) = *(const uint4*)t;
}

// ---------------- fused GEMM + LSTM epilogue, 4-phase counted-vmcnt --------
// Block 512 thr (8 waves, 2M x 4N). Tile: 256 rows x 64 h x 4 gates. BK=64.
// LDS 128 KiB: sA[2][256][64], sW[2][4][64][64] double-buffered.
// Staging: 8 units/K-tile (W0..W3, Au0,Au2,Au1,Au3), 1 gload_lds instr/wave
// each, issued 2/phase one tile ahead. Waits: vmcnt(4)@ph0, vmcnt(6)@ph2 only.
// Chunk-XOR swizzle (proven round 1): LDS row holds chunk c at c^(row&7),
// achieved by pre-swizzling the per-lane GLOBAL source column.
struct PhaseRegs {
  f32x4 (&acc)[4][8];
  const bf16x8 (&bfr)[4][2];
};

template<int MB>
__device__ __forceinline__ void do_phase(
    const __hip_bfloat16 (*sAp)[64], f32x4 (&acc)[4][8],
    const bf16x8 (&bfr)[4][2], int arow, int chk0, int chk1) {
  bf16x8 a00 = *(const bf16x8*)&sAp[arow + MB * 16][chk0];
  bf16x8 a01 = *(const bf16x8*)&sAp[arow + MB * 16][chk1];
  bf16x8 a10 = *(const bf16x8*)&sAp[arow + (MB + 1) * 16][chk0];
  bf16x8 a11 = *(const bf16x8*)&sAp[arow + (MB + 1) * 16][chk1];
  __builtin_amdgcn_s_setprio(1);
#pragma unroll
  for (int g = 0; g < 4; ++g) {
    mfma_16x16x32_bf16(acc[g][MB],     a00, bfr[g][0]);
    mfma_16x16x32_bf16(acc[g][MB],     a01, bfr[g][1]);
    mfma_16x16x32_bf16(acc[g][MB + 1], a10, bfr[g][0]);
    mfma_16x16x32_bf16(acc[g][MB + 1], a11, bfr[g][1]);
  }
  __builtin_amdgcn_s_setprio(0);
}

__global__ __launch_bounds__(512, 2) void lstm_gemm_kernel(
    const __hip_bfloat16* __restrict__ A,   // [8192][2048]
    const __hip_bfloat16* __restrict__ W,   // [4096][2048] gate-major
    const float* __restrict__ cx,
    const float* __restrict__ bxi, const float* __restrict__ bhi,
    const float* __restrict__ bxf, const float* __restrict__ bhf,
    const float* __restrict__ bxc, const float* __restrict__ bhc,
    const float* __restrict__ bxo, const float* __restrict__ bho,
    float* __restrict__ hy, float* __restrict__ cy) {

  __shared__ __align__(16) __hip_bfloat16 sA[2][256][64];
  __shared__ __align__(16) __hip_bfloat16 sW[2][4][64][64];

  const int tid  = threadIdx.x;
  const int w    = tid >> 6;
  const int lane = tid & 63;
  const int wm = w >> 2, wn = w & 3;
  const int lq = lane >> 4, lr16 = lane & 15;

  // XCD-aware bijective swizzle (512 % 8 == 0)
  const int bid = blockIdx.x;
  const int swz = (bid & 7) * 64 + (bid >> 3);
  const int row0 = (swz >> 4) * 256;
  const int col0 = (swz & 15) * 64;

  // staging: thread covers (row-in-unit = tid>>3, chunk = tid&7)
  const int srow = tid >> 3;
  const int scs  = (tid & 7) ^ (srow & 7);
  const __hip_bfloat16* Asrc = A + (size_t)(row0 + srow) * K_DIM + scs * 8;
  const __hip_bfloat16* Wsrc = W + (size_t)(col0 + srow) * K_DIM + scs * 8;
  const size_t Wg = (size_t)H_DIM * K_DIM;   // per-gate stride in W

  // ds_read chunk offsets (element idx): (ks*4+lq) ^ (lr16&7), *8
  const int chk0 = ((lq)     ^ (lr16 & 7)) * 8;
  const int chk1 = ((4 + lq) ^ (lr16 & 7)) * 8;
  const int arow = wm * 128 + lr16;
  const int wrow = wn * 16 + lr16;

  f32x4 acc[4][8];
#pragma unroll
  for (int g = 0; g < 4; ++g)
#pragma unroll
    for (int m = 0; m < 8; ++m)
      acc[g][m] = (f32x4){0.f, 0.f, 0.f, 0.f};

#define ISSUE_W2(P, KT, G0)                                                    \
  {                                                                            \
    const size_t kof = (size_t)(KT) * 64;                                      \
    gload16(Wsrc + (size_t)(G0) * Wg + kof,                                    \
            (char*)&sW[P][G0][0][0] + tid * 16);                               \
    gload16(Wsrc + (size_t)((G0) + 1) * Wg + kof,                              \
            (char*)&sW[P][(G0) + 1][0][0] + tid * 16);                         \
  }
#define ISSUE_A2(P, KT, R0, R1)                                                \
  {                                                                            \
    const size_t kof = (size_t)(KT) * 64;                                      \
    gload16(Asrc + (size_t)(R0) * K_DIM + kof,                                 \
            (char*)&sA[P][R0][0] + tid * 16);                                  \
    gload16(Asrc + (size_t)(R1) * K_DIM + kof,                                 \
            (char*)&sA[P][R1][0] + tid * 16);                                  \
  }

  // prologue: stage tile 0 -> buf 0 in order W0..W3, Au0, Au2, Au1, Au3
  ISSUE_W2(0, 0, 0);
  ISSUE_W2(0, 0, 2);
  ISSUE_A2(0, 0, 0, 128);
  ISSUE_A2(0, 0, 64, 192);

  for (int t = 0; t < NT; ++t) {
    const int p  = t & 1;
    const int q  = p ^ 1;
    const int tn = (t + 1 < NT) ? t + 1 : NT - 1;  // clamped: uniform vmcnt
    const __hip_bfloat16(*sAp)[64] = sA[p];

    // ---- ph0: need W*, Au0, Au2 of tile t; allow {Au1,Au3, 2 new} ----
    ISSUE_W2(q, tn, 0);
    asm volatile("s_waitcnt vmcnt(4)\n\ts_barrier" ::: "memory");
    bf16x8 bfr[4][2];
#pragma unroll
    for (int g = 0; g < 4; ++g) {
      bfr[g][0] = *(const bf16x8*)&sW[p][g][wrow][chk0];
      bfr[g][1] = *(const bf16x8*)&sW[p][g][wrow][chk1];
    }
    do_phase<0>(sAp, acc, bfr, arow, chk0, chk1);

    // ---- ph1 ----
    ISSUE_W2(q, tn, 2);
    do_phase<2>(sAp, acc, bfr, arow, chk0, chk1);

    // ---- ph2: need Au1, Au3; allow the 6 tile-(t+1) units in flight ----
    ISSUE_A2(q, tn, 0, 128);
    asm volatile("s_waitcnt vmcnt(6)\n\ts_barrier" ::: "memory");
    do_phase<4>(sAp, acc, bfr, arow, chk0, chk1);

    // ---- ph3 ----
    ISSUE_A2(q, tn, 64, 192);
    do_phase<6>(sAp, acc, bfr, arow, chk0, chk1);
  }

  // ---- epilogue ----
  const int h = col0 + wrow;
  const float bi = bxi[h] + bhi[h];
  const float bf = bxf[h] + bhf[h];
  const float bc = bxc[h] + bhc[h];
  const float bo = bxo[h] + bho[h];
#pragma unroll
  for (int m = 0; m < 8; ++m) {
#pragma unroll
    for (int j = 0; j < 4; ++j) {
      const int r = row0 + wm * 128 + m * 16 + lq * 4 + j;
      const size_t o = (size_t)r * H_DIM + h;
      const float ig = fast_sigmoid(acc[0][m][j] + bi);
      const float fg = fast_sigmoid(acc[1][m][j] + bf);
      const float gg = fast_tanh   (acc[2][m][j] + bc);
      const float og = fast_sigmoid(acc[3][m][j] + bo);
      const float c  = cx[o] * fg + ig * gg;
      cy[o] = c;
      hy[o] = og * fast_tanh(c);
    }
  }
#undef ISSUE_W2
#undef ISSUE_A2
}

extern "C" void kernel_launch(void* const* d_in, const int* in_sizes, int n_in,
                              void* d_out, int out_size, void* d_ws, size_t ws_size,
                              hipStream_t stream) {
  const float* x   = (const float*)d_in[0];
  const float* hx  = (const float*)d_in[1];
  const float* cx  = (const float*)d_in[2];
  const float* wxi = (const float*)d_in[4];  const float* bxi = (const float*)d_in[5];
  const float* wxf = (const float*)d_in[6];  const float* bxf = (const float*)d_in[7];
  const float* wxc = (const float*)d_in[8];  const float* bxc = (const float*)d_in[9];
  const float* wxo = (const float*)d_in[10]; const float* bxo = (const float*)d_in[11];
  const float* whi = (const float*)d_in[12]; const float* bhi = (const float*)d_in[13];
  const float* whf = (const float*)d_in[14]; const float* bhf = (const float*)d_in[15];
  const float* whc = (const float*)d_in[16]; const float* bhc = (const float*)d_in[17];
  const float* who = (const float*)d_in[18]; const float* bho = (const float*)d_in[19];

  __hip_bfloat16* Abf = (__hip_bfloat16*)d_ws;
  __hip_bfloat16* Wbf = (__hip_bfloat16*)((char*)d_ws + (size_t)B_DIM * K_DIM * 2);

  float* hy  = (float*)d_out;
  float* cyo = (float*)d_out + (size_t)B_DIM * H_DIM;

  pack_a_kernel<<<(B_DIM * K_DIM / 8) / 256, 256, 0, stream>>>(x, hx, Abf);
  pack_w_kernel<<<(4 * H_DIM * K_DIM / 8) / 256, 256, 0, stream>>>(
      wxi, wxf, wxc, wxo, whi, whf, whc, who, Wbf);

  lstm_gemm_kernel<<<dim3(512), 512, 0, stream>>>(
      Abf, Wbf, cx, bxi, bhi, bxf, bhf, bxc, bhc, bxo, bho, hy, cyo);
}